// Round 12
// baseline (916.788 us; speedup 1.0000x reference)
//
#include <hip/hip_runtime.h>
#include <math.h>

#define NN 1000
#define INF_ 32
#define H 128
#define M 128
#define DEG 16
#define PP 2
#define OUTF 10
#define MAXM (10 * NN)        // scan length; head <= MAXM
#define QCAP (MAXM + DEG)     // only entries < MAXM are ever read
#define NSLOT (MAXM + 128)    // nmbuf rows: nstart + total procs
#define NT 1024               // 16 waves, 4/SIMD (VGPR cap 128!)
#define RCH 32                // rows per chunk (two 16-row wave-tiles)
#define WROW 264              // padded halves per X/weight row (256+8)
#define NROW 136              // padded halves per NSh row (128+8)

typedef _Float16 half8 __attribute__((ext_vector_type(8)));
typedef float floatx4 __attribute__((ext_vector_type(4)));

// LDS-only barrier: publishes LDS writes without draining global (vmcnt) queue.
__device__ __forceinline__ void bar_lds() {
    asm volatile("s_waitcnt lgkmcnt(0)\n\ts_barrier" ::: "memory");
}

__global__ __launch_bounds__(128)
void init_kernel(const float* __restrict__ xa, const float* __restrict__ fm,
                 const float* __restrict__ enc_w, const float* __restrict__ enc_b,
                 const int* __restrict__ nstart_p,
                 _Float16* __restrict__ feats_h, float* __restrict__ finalv,
                 _Float16* __restrict__ nmbuf_h) {
    int b = blockIdx.x, t = threadIdx.x;
    float acc = enc_b[t];
    const float* xr = xa + b * INF_;
#pragma unroll
    for (int k = 0; k < INF_; ++k) acc += xr[k] * enc_w[k * H + t];
    feats_h[b * H + t] = (_Float16)acc;     // same rounding point as R8..R11
    finalv[b * H + t] = 0.0f;
    if (b < nstart_p[0]) nmbuf_h[(size_t)b * M + t] = (_Float16)fm[b * M + t];
}

// Pack weights fp16 transposed [n][k] with +8 pad: wB[n*WROW+k] = w[k][n].
__global__ __launch_bounds__(256)
void pack_kernel(const float* __restrict__ ns_w, const float* __restrict__ nm_w,
                 _Float16* __restrict__ wnsB, _Float16* __restrict__ wnmB) {
    const int idx = blockIdx.x * 256 + threadIdx.x;   // 128*WROW
    if (idx >= 128 * WROW) return;
    const int n = idx / WROW, k = idx % WROW;
    wnsB[idx] = (k < 256) ? (_Float16)ns_w[k * H + n] : (_Float16)0.0f;
    wnmB[idx] = (k < 256) ? (_Float16)nm_w[k * M + n] : (_Float16)0.0f;
}

// Rank-decomposed sequential ACT loop; MFMA matvecs, register-resident weight
// B-fragments; 16 waves: waves 0-7 do rows 0-15, waves 8-15 rows 16-31 of each
// 32-row chunk. 2 LDS barriers per chunk (new_act recomputed redundantly from
// (rz, rta) — bit-identical to the single-writer form).
__global__ __launch_bounds__(NT, 1)
void seq_kernel(const int* __restrict__ neighbors,
                const float* __restrict__ ns_b, const float* __restrict__ nm_b,
                const float* __restrict__ act_w, const float* __restrict__ act_b,
                const float* __restrict__ dec_w, const float* __restrict__ dec_b,
                const int* __restrict__ nstart_p,
                const _Float16* __restrict__ wnsB, const _Float16* __restrict__ wnmB,
                _Float16* __restrict__ feats_h, float* __restrict__ finalv,
                _Float16* __restrict__ nmbuf_h, unsigned int* __restrict__ qpack,
                float* __restrict__ out) {
    __shared__ __align__(16) _Float16 s_Xh[RCH * WROW];  // 16896 B
    __shared__ __align__(16) _Float16 s_NSh[RCH * NROW]; // 8704 B
    __shared__ float s_tact[NN];                         // 4000 B
    __shared__ int   s_mark[NN];                         // 4000 B (order/readout overlay)
    __shared__ float s_actw[H + M];
    __shared__ float s_nsb[H];
    __shared__ float s_nmb[M];
    __shared__ float s_rz[RCH];
    __shared__ float s_rta[NT];                          // round-start tact per row
    __shared__ unsigned short s_rnode[NT];
    __shared__ unsigned short s_rslot[NT];
    __shared__ unsigned int  s_enq[NT];                  // node|newslot<<16 per entry
    __shared__ unsigned char s_flag[NT];
    __shared__ int s_wb[16], s_wc[16];

    short* s_order = (short*)s_mark;                     // overlay: mark[0..511]
    float* s_g  = (float*)(s_mark + 512);                // overlay: readout only
    float* s_lg = (float*)(s_mark + 512 + 128);

    const int t = threadIdx.x;
    const int lane = t & 63, wid = t >> 6;               // wid 0..15
    const int quad = lane >> 4, lm = lane & 15;
    const int rowb = (wid >> 3) << 4;                    // wave-tile row base (0/16)
    const int colw = ((wid & 7) << 4) + lm;              // this thread's output col
    const int sg = t & 31;                               // gate sub-lane
    const int r32 = t >> 5, c8 = t & 31;                 // staging coords (32x32)
    const int nstart = nstart_p[0];

    // ---- one-time: weight B-fragments into registers (loop-invariant) ----
    half8 wbn[8], wbm[8];
#pragma unroll
    for (int c = 0; c < 8; ++c) {
        wbn[c] = *(const half8*)(wnsB + (size_t)colw * WROW + (c << 5) + (quad << 3));
        wbm[c] = *(const half8*)(wnmB + (size_t)colw * WROW + (c << 5) + (quad << 3));
    }

    for (int i = t; i < NN; i += NT) { s_tact[i] = 0.0f; s_mark[i] = 0x7fffffff; }
    for (int i = t; i < nstart; i += NT) qpack[i] = (unsigned)i | ((unsigned)i << 16);
    if (t < H + M) s_actw[t] = act_w[t];
    if (t < H) { s_nsb[t] = ns_b[t]; s_nmb[t] = nm_b[t]; }
    const float actb = act_b[0];
    __syncthreads();
    const float nsb_c = s_nsb[colw];
    const float nmb_c = s_nmb[colw];
    float aw[8];
#pragma unroll
    for (int j = 0; j < 8; ++j) aw[j] = s_actw[sg * 8 + j];

    int head = 0, tail = nstart, gbase = nstart;
    for (;;) {
        const int lim = min(tail, MAXM);
        if (head >= lim) break;
        const int W = min(NT, lim - head);

        // ---- classify; clear flags; repair order-overlaid mark ----
        int node = 0, slotv = 0; bool cand0 = false;
        if (t < W) {
            const unsigned v = qpack[head + t];
            node = (int)(v & 0xffffu);
            slotv = (int)(v >> 16);
            cand0 = (s_tact[node] <= 1.0f - 1e-7f);
        }
        s_flag[t] = 0;
        if (t < 512) s_mark[t] = 0x7fffffff;
        bar_lds();                                       // B1
        bool remaining = cand0;

        // ---------------- rank rounds ----------------
        int base = 0;
        for (;;) {
            float tav = 0.0f;
            bool rem2 = false;
            if (remaining) { tav = s_tact[node]; rem2 = (tav <= 1.0f - 1e-7f); }
            if (rem2) atomicMin(&s_mark[node], t);
            bar_lds();                                   // R1
            const bool win = rem2 && (s_mark[node] == t);
            const unsigned long long mw = __ballot(win);
            if (lane == 0) s_wb[wid] = __popcll(mw);
            bar_lds();                                   // R2
            int Pr = 0, preb = 0;
#pragma unroll
            for (int w = 0; w < 16; ++w) { Pr += s_wb[w]; preb += (w < wid) ? s_wb[w] : 0; }
            if (Pr == 0) break;
            const int wrank = preb + __popcll(mw & ((1ull << lane) - 1ull));
            if (win) {
                s_rnode[wrank] = (unsigned short)node;
                s_rslot[wrank] = (unsigned short)slotv;
                s_rta[wrank] = tav;
                s_enq[t] = (unsigned)node | ((unsigned)(gbase + base + wrank) << 16);
                s_flag[t] = 1;
            }
            if (rem2) s_mark[node] = 0x7fffffff;         // reset touched entries
            remaining = rem2 && !win;
            bar_lds();                                   // R3: rnode/rslot/rta ready

            // ---- prefetch chunk 0 (X row uint4 + finalv vals) ----
            uint4 px; float fv[4];
            {
                const int rr = min(r32, Pr - 1);
                const int nr = (int)s_rnode[rr];
                const int sl = (int)s_rslot[rr];
                px = (c8 < 16)
                    ? ((const uint4*)(feats_h + (size_t)nr * H))[c8]
                    : ((const uint4*)(nmbuf_h + (size_t)sl * M))[c8 - 16];
#pragma unroll
                for (int i = 0; i < 4; ++i) {
                    const int rr2 = min(rowb + (quad << 2) + i, Pr - 1);
                    fv[i] = finalv[(size_t)s_rnode[rr2] * H + colw];
                }
            }
            // ---- chunks of 32 rows, software-pipelined staging ----
            for (int c0 = 0; c0 < Pr; c0 += RCH) {
                const int Pc = min(RCH, Pr - c0);
                *(uint4*)(s_Xh + r32 * WROW + (c8 << 3)) = px;
                bar_lds();                               // A: Xh(c) ready
                const bool hasnext = (c0 + RCH) < Pr;
                uint4 pxn; float fvn[4];
                if (hasnext) {                           // issue next-chunk loads
                    const int rr = min(c0 + RCH + r32, Pr - 1);
                    const int nr = (int)s_rnode[rr];
                    const int sl = (int)s_rslot[rr];
                    pxn = (c8 < 16)
                        ? ((const uint4*)(feats_h + (size_t)nr * H))[c8]
                        : ((const uint4*)(nmbuf_h + (size_t)sl * M))[c8 - 16];
#pragma unroll
                    for (int i = 0; i < 4; ++i) {
                        const int rr2 = min(c0 + RCH + rowb + (quad << 2) + i, Pr - 1);
                        fvn[i] = finalv[(size_t)s_rnode[rr2] * H + colw];
                    }
                }
                // gate partials (f32 math on fp16 x; coeffs in regs)
                {
                    const int r = t >> 5;
                    if (r < Pc) {
                        const half8 hv = *(const half8*)(s_Xh + r * WROW + (sg << 3));
                        float p = 0.0f;
#pragma unroll
                        for (int j = 0; j < 8; ++j) p += (float)hv[j] * aw[j];
#pragma unroll
                        for (int off = 16; off > 0; off >>= 1) p += __shfl_down(p, off, 32);
                        if (sg == 0) s_rz[r] = p;
                    }
                }
                // phase 1 MFMA: ns (K=256) + nm msg-half (K=128..256); B from regs
                floatx4 accn = {0.0f, 0.0f, 0.0f, 0.0f};
                floatx4 accm = {0.0f, 0.0f, 0.0f, 0.0f};
                {
                    const _Float16* xrow = s_Xh + (rowb + lm) * WROW + (quad << 3);
                    half8 a[8];
#pragma unroll
                    for (int c = 0; c < 8; ++c) a[c] = *(const half8*)(xrow + (c << 5));
#pragma unroll
                    for (int c = 0; c < 8; ++c)
                        accn = __builtin_amdgcn_mfma_f32_16x16x32_f16(
                            a[c], wbn[c], accn, 0, 0, 0);
#pragma unroll
                    for (int c = 4; c < 8; ++c)
                        accm = __builtin_amdgcn_mfma_f32_16x16x32_f16(
                            a[c], wbm[c], accm, 0, 0, 0);
                }
                float nsv[4];
#pragma unroll
                for (int i = 0; i < 4; ++i) {
                    const int r = rowb + (quad << 2) + i;
                    nsv[i] = fmaxf(accn[i] + nsb_c, 0.0f);
                    if (r < Pc) {
                        s_NSh[r * NROW + colw] = (_Float16)nsv[i];
                        feats_h[(size_t)s_rnode[c0 + r] * H + colw] = (_Float16)nsv[i];
                    }
                }
                bar_lds();                               // B: Xh reads done; NSh+rz ready

                // new_act recomputed redundantly (bit-identical ops); tact update
                // by t<Pc (writes ordered vs next round by R7 full sync)
                float na[4];
#pragma unroll
                for (int i = 0; i < 4; ++i) {
                    const int r = rowb + (quad << 2) + i;
                    if (r < Pc) {
                        const float z = s_rz[r] + actb;
                        const float cnd = 1.0f / (1.0f + expf(-z));
                        const float ta = s_rta[c0 + r];
                        na[i] = (ta + cnd > 1.0f) ? (1.0f - ta) : cnd;
                    }
                }
                if (t < Pc) {
                    const float z = s_rz[t] + actb;
                    const float cnd = 1.0f / (1.0f + expf(-z));
                    const float ta = s_rta[c0 + t];
                    const float nat = (ta + cnd > 1.0f) ? (1.0f - ta) : cnd;
                    s_tact[(int)s_rnode[c0 + t]] = ta + nat;
                }
                // phase 2 MFMA: nm ns-half (K=0..128); B from regs; nmbuf store
                {
                    const _Float16* nrow = s_NSh + (rowb + lm) * NROW + (quad << 3);
#pragma unroll
                    for (int c = 0; c < 4; ++c)
                        accm = __builtin_amdgcn_mfma_f32_16x16x32_f16(
                            *(const half8*)(nrow + (c << 5)), wbm[c], accm, 0, 0, 0);
                }
#pragma unroll
                for (int i = 0; i < 4; ++i) {
                    const int r = rowb + (quad << 2) + i;
                    if (r < Pc) {
                        nmbuf_h[(size_t)(gbase + base + c0 + r) * M + colw] =
                            (_Float16)(accm[i] + nmb_c);
                        finalv[(size_t)s_rnode[c0 + r] * H + colw] =
                            fv[i] + nsv[i] * na[i];
                    }
                }
                if (hasnext) {
                    px = pxn;
#pragma unroll
                    for (int i = 0; i < 4; ++i) fv[i] = fvn[i];
                }
            }
            base += Pr;
            __syncthreads();       // R7 (full): drain feats/nmbuf/finalv stores
        }

        // ---------------- enqueue (queue order via prefix over flags) ----------------
        const bool pf = (s_flag[t] != 0);
        const unsigned long long mf = __ballot(pf);
        if (lane == 0) s_wc[wid] = __popcll(mf);
        bar_lds();                                       // B3
        int T = 0, prec = 0;
#pragma unroll
        for (int w = 0; w < 16; ++w) { T += s_wc[w]; prec += (w < wid) ? s_wc[w] : 0; }
        if (pf) s_order[prec + __popcll(mf & ((1ull << lane) - 1ull))] = (short)t;
        bar_lds();                                       // B4
        for (int idx = t; idx < T * DEG; idx += NT) {
            const int e = (int)s_order[idx >> 4];
            const unsigned v = s_enq[e];
            const int nd = (int)(v & 0xffffu);
            const unsigned slot = v >> 16;
            const int q = tail + idx;
            if (q < QCAP)
                qpack[q] = (unsigned)neighbors[nd * DEG + (idx & 15)] | (slot << 16);
        }
        tail += DEG * T;
        gbase += T;
        head += W;
        __syncthreads();                                 // B5 (full): qpack visible
    }

    // ---- readout (g/lg overlaid on dead mark region) ----
    if (t < H) {
        float g0 = 0, g1 = 0, g2 = 0, g3 = 0;
        for (int n = 0; n < NN; n += 4) {
            g0 += finalv[(n + 0) * H + t];
            g1 += finalv[(n + 1) * H + t];
            g2 += finalv[(n + 2) * H + t];
            g3 += finalv[(n + 3) * H + t];
        }
        s_g[t] = (g0 + g1) + (g2 + g3);
    }
    __syncthreads();
    if (t < PP * OUTF) {
        const int pp = t / OUTF, o = t % OUTF;
        float acc = dec_b[pp * OUTF + o];
        for (int h = 0; h < H; ++h) acc += s_g[h] * dec_w[(pp * H + h) * OUTF + o];
        s_lg[t] = acc;
    }
    __syncthreads();
    if (t < PP * OUTF) {
        const int pp = t / OUTF;
        float mx = -INFINITY;
        for (int o = 0; o < OUTF; ++o) mx = fmaxf(mx, s_lg[pp * OUTF + o]);
        float s = 0.0f;
        for (int o = 0; o < OUTF; ++o) s += expf(s_lg[pp * OUTF + o] - mx);
        out[t] = s_lg[t] - (mx + logf(s));
    }
}

extern "C" void kernel_launch(void* const* d_in, const int* in_sizes, int n_in,
                              void* d_out, int out_size, void* d_ws, size_t ws_size,
                              hipStream_t stream) {
    const float* xa        = (const float*)d_in[0];
    const float* fm        = (const float*)d_in[1];
    const int*   neighbors = (const int*)  d_in[2];
    const int*   nstart_p  = (const int*)  d_in[3];
    const float* enc_w     = (const float*)d_in[4];
    const float* enc_b     = (const float*)d_in[5];
    const float* ns_w      = (const float*)d_in[6];
    const float* ns_b      = (const float*)d_in[7];
    const float* nm_w      = (const float*)d_in[8];
    const float* nm_b      = (const float*)d_in[9];
    const float* act_w     = (const float*)d_in[10];
    const float* act_b     = (const float*)d_in[11];
    const float* dec_w     = (const float*)d_in[12];
    const float* dec_b     = (const float*)d_in[13];
    float* out = (float*)d_out;

    char* w = (char*)d_ws;
    _Float16* feats_h = (_Float16*)w;                 w += (size_t)NN * H * 2;
    float*    finalv  = (float*)w;                    w += (size_t)NN * H * 4;
    _Float16* nmbuf_h = (_Float16*)w;                 w += (size_t)NSLOT * M * 2;
    _Float16* wnsB    = (_Float16*)w;                 w += (size_t)128 * WROW * 2;
    _Float16* wnmB    = (_Float16*)w;                 w += (size_t)128 * WROW * 2;
    unsigned int* qpack = (unsigned int*)w;

    init_kernel<<<NN, 128, 0, stream>>>(xa, fm, enc_w, enc_b, nstart_p,
                                        feats_h, finalv, nmbuf_h);
    pack_kernel<<<132, 256, 0, stream>>>(ns_w, nm_w, wnsB, wnmB);
    seq_kernel<<<1, NT, 0, stream>>>(neighbors, ns_b, nm_b,
                                     act_w, act_b, dec_w, dec_b, nstart_p,
                                     wnsB, wnmB,
                                     feats_h, finalv, nmbuf_h, qpack, out);
}